// Round 5
// baseline (183.488 us; speedup 1.0000x reference)
//
#include <hip/hip_runtime.h>

// GridSample1d, align_corners=True, border padding.
// inp [64,64,4096] f32, grid [64,8192] f32, out [64,64,8192] f32.
//
// R9: occupancy ladder continued. Kernel time ranks exactly by
// (blocks/CU, waves/CU): R7(2,8)=31us, R6(2,16)=28, R5(4,16)=24.2,
// R8(5,20)=23.4. This round targets the max wave slots: BLOCK=512, CPB=2
// -> EPT=16, index arrays w1[16]+lpk[8]=24 regs -> fits the <=64-VGPR
// class -> launch_bounds(512,8) = 8 waves/SIMD = 32 waves/CU = 4 resident
// blocks x 32 KB = 128 KB LDS. Same CPB=2 redundancy amortization and
// 4-block stagger as R5, +60% waves vs R8 to overlap DMA-drain, the
// conflicted random-index LDS gather, and the NT-store stream.
// Structure otherwise identical: [DMA -> index cover phase -> syncthreads
// -> LDS gather + NT float4 stores].

constexpr int N_    = 64;
constexpr int C_    = 64;
constexpr int L_IN  = 4096;
constexpr int L_OUT = 8192;

constexpr int BLOCK = 512;
constexpr int CPB   = 2;                   // channels per block
constexpr int EPT   = L_OUT / BLOCK;       // 16 grid points per thread
constexpr int NCH   = EPT / 4;             // 4 float4 chunks
constexpr int KSTEP = L_IN / (BLOCK * 4);  // 2 DMA chunks per row
constexpr int NBLOCKS = N_ * C_ / CPB;     // 2048

typedef float f32x4 __attribute__((ext_vector_type(4)));

__global__ __launch_bounds__(BLOCK, 8) void gs1d_kernel(
    const float* __restrict__ inp, const float* __restrict__ grid,
    float* __restrict__ out)
{
    __shared__ float row[CPB][L_IN];  // 32 KB

    const int tid = threadIdx.x;
    const int bid = blockIdx.x;           // n*32 + c/2
    const int n   = bid >> 5;
    const int c0  = (bid & 31) * CPB;

    // Stage CPB input rows -> LDS: 4 x (512 lanes x 16 B) async DMA.
    // LDS dest semantics: wave-uniform base + lane*16 (m97/m104) -> linear.
    const float* src = inp + (size_t)(n * C_ + c0) * L_IN;
#pragma unroll
    for (int r = 0; r < CPB; ++r) {
#pragma unroll
        for (int k = 0; k < KSTEP; ++k) {
            int e     = (k * BLOCK + tid) * 4;          // per-lane float index
            int lbase = (k * BLOCK + (tid & ~63)) * 4;  // wave-uniform float index
            __builtin_amdgcn_global_load_lds(
                (const __attribute__((address_space(1))) void*)(src + r * L_IN + e),
                (__attribute__((address_space(3))) void*)(&row[r][lbase]),
                16, 0, 0);
        }
    }

    const float* grow = grid + (size_t)n * L_OUT;

    // Pre-barrier: all grid loads + index math in registers; this VALU phase
    // (plus the grid-load latency) covers the DMA's in-flight time.
    // li packed 2 x u16 per reg (exact: li <= 4094 < 2^16).
    unsigned lpk[EPT / 2];
    float    w1[EPT];
#pragma unroll
    for (int h = 0; h < NCH; ++h) {
        float4 g = *reinterpret_cast<const float4*>(grow + h * (BLOCK * 4) + 4 * tid);
        const float* gp = &g.x;
#pragma unroll
        for (int j = 0; j < 4; ++j) {
            int p = h * 4 + j;
            // exact reference op order: ((g+1)*0.5)*(L-1), clip, floor
            float x = (gp[j] + 1.0f) * 0.5f * (float)(L_IN - 1);
            x = fminf(fmaxf(x, 0.0f), (float)(L_IN - 1));
            float xf = floorf(x);
            int   i0 = (int)xf;
            float w  = x - xf;
            // boundary: at i0==L-1 shift to (li=L-2, w1=1) so the
            // unconditional lerp a + w1*(b-a) stays exact.
            int   qi = min(i0, L_IN - 2);
            w1[p] = (i0 >= L_IN - 1) ? 1.0f : w;
            if ((p & 1) == 0) lpk[p >> 1]  = (unsigned)qi;
            else              lpk[p >> 1] |= (unsigned)qi << 16;
        }
    }

    __syncthreads();  // DMA latency already covered by the index phase

    float* orow = out + (size_t)(n * C_ + c0) * L_OUT;

    // Post-barrier: LDS gather + lerp for both rows off the shared indices,
    // nontemporal coalesced float4 stores (output is never re-read).
#pragma unroll
    for (int h = 0; h < NCH; ++h) {
        f32x4 o0, o1;
#pragma unroll
        for (int j = 0; j < 4; ++j) {
            int   p  = h * 4 + j;
            int   q  = (int)((lpk[p >> 1] >> (16 * (p & 1))) & 0xffffu);  // v_bfe_u32
            float a0 = row[0][q];        // ds_read2_b32 pair
            float b0 = row[0][q + 1];
            float a1 = row[1][q];        // same vaddr, offset:16384
            float b1 = row[1][q + 1];
            o0[j] = fmaf(w1[p], b0 - a0, a0);
            o1[j] = fmaf(w1[p], b1 - a1, a1);
        }
        __builtin_nontemporal_store(o0,
            reinterpret_cast<f32x4*>(orow + h * (BLOCK * 4) + 4 * tid));
        __builtin_nontemporal_store(o1,
            reinterpret_cast<f32x4*>(orow + L_OUT + h * (BLOCK * 4) + 4 * tid));
    }
}

extern "C" void kernel_launch(void* const* d_in, const int* in_sizes, int n_in,
                              void* d_out, int out_size, void* d_ws, size_t ws_size,
                              hipStream_t stream) {
    const float* inp  = (const float*)d_in[0];
    const float* grid = (const float*)d_in[1];
    float* out = (float*)d_out;
    gs1d_kernel<<<NBLOCKS, BLOCK, 0, stream>>>(inp, grid, out);
}

// Round 6
// 182.939 us; speedup vs baseline: 1.0030x; 1.0030x over previous
//
#include <hip/hip_runtime.h>

// GridSample1d, align_corners=True, border padding.
// inp [64,64,4096] f32, grid [64,8192] f32, out [64,64,8192] f32.
//
// R10 = revert to R8, the session's best-measured kernel (~23.4us kernel
// time after subtracting the 2x ~78-80us poison fills in the timed region).
// Ladder summary (kernel us): R7(2blk,8w)=31, R6(2,16)=28, R5(4,16)=24.2,
// R8(5,20)=23.4, R9(512thr/8w attempt)=24.6. Occupancy lever exhausted.
//
// Roofline arithmetic: mandatory 134.2 MB NT writes + ~69 MB reads.
// If reads were all-HBM, floor = 203MB/8TB/s = 25.4us at SPEC peak; R8 runs
// 23.4us, i.e. faster than spec-peak total-bytes -> reads partially L3-hit
// and the HBM bus is saturated. Writes alone = 5.74 TB/s concurrent with
// the read stream. No software lever remains above the bus.
//
// Structure: 5 blocks/CU (launch_bounds(256,5), li packed 2xu16 -> VGPR<=102,
// 5 x 32KB = 160KB LDS exactly), per-block [8x16B global_load_lds DMA ->
// grid-load + index cover phase -> syncthreads -> LDS gather + NT f32x4
// stores]. CPB=2 amortizes grid/index math across channels.

constexpr int N_    = 64;
constexpr int C_    = 64;
constexpr int L_IN  = 4096;
constexpr int L_OUT = 8192;

constexpr int BLOCK = 256;
constexpr int CPB   = 2;                  // channels per block
constexpr int EPT   = L_OUT / BLOCK;      // 32 grid points per thread
constexpr int NCH   = EPT / 4;            // 8 float4 chunks
constexpr int NBLOCKS = N_ * C_ / CPB;    // 2048

typedef float f32x4 __attribute__((ext_vector_type(4)));

__global__ __launch_bounds__(BLOCK, 5) void gs1d_kernel(
    const float* __restrict__ inp, const float* __restrict__ grid,
    float* __restrict__ out)
{
    __shared__ float row[CPB][L_IN];  // 32 KB

    const int tid = threadIdx.x;
    const int bid = blockIdx.x;           // n*32 + c/2
    const int n   = bid >> 5;
    const int c0  = (bid & 31) * CPB;

    // Stage CPB input rows -> LDS: 8 x (256 lanes x 16 B) async DMA.
    // LDS dest semantics: wave-uniform base + lane*16 (m97/m104) -> linear.
    const float* src = inp + (size_t)(n * C_ + c0) * L_IN;
#pragma unroll
    for (int r = 0; r < CPB; ++r) {
#pragma unroll
        for (int k = 0; k < 4; ++k) {
            int e     = (k * BLOCK + tid) * 4;          // per-lane float index
            int lbase = (k * BLOCK + (tid & ~63)) * 4;  // wave-uniform float index
            __builtin_amdgcn_global_load_lds(
                (const __attribute__((address_space(1))) void*)(src + r * L_IN + e),
                (__attribute__((address_space(3))) void*)(&row[r][lbase]),
                16, 0, 0);
        }
    }

    const float* grow = grid + (size_t)n * L_OUT;

    // Pre-barrier: all grid loads + index math in registers; this VALU phase
    // (plus the grid-load latency) covers the 32 KB DMA's in-flight time.
    // li packed 2 x u16 per reg (exact: li <= 4094 < 2^16).
    unsigned lpk[EPT / 2];
    float    w1[EPT];
#pragma unroll
    for (int h = 0; h < NCH; ++h) {
        float4 g = *reinterpret_cast<const float4*>(grow + h * (BLOCK * 4) + 4 * tid);
        const float* gp = &g.x;
#pragma unroll
        for (int j = 0; j < 4; ++j) {
            int p = h * 4 + j;
            // exact reference op order: ((g+1)*0.5)*(L-1), clip, floor
            float x = (gp[j] + 1.0f) * 0.5f * (float)(L_IN - 1);
            x = fminf(fmaxf(x, 0.0f), (float)(L_IN - 1));
            float xf = floorf(x);
            int   i0 = (int)xf;
            float w  = x - xf;
            // boundary: at i0==L-1 shift to (li=L-2, w1=1) so the
            // unconditional lerp a + w1*(b-a) stays exact.
            int   qi = min(i0, L_IN - 2);
            w1[p] = (i0 >= L_IN - 1) ? 1.0f : w;
            if ((p & 1) == 0) lpk[p >> 1]  = (unsigned)qi;
            else              lpk[p >> 1] |= (unsigned)qi << 16;
        }
    }

    __syncthreads();  // DMA latency already covered by the index phase

    float* orow = out + (size_t)(n * C_ + c0) * L_OUT;

    // Post-barrier: LDS gather + lerp for both rows off the shared indices,
    // nontemporal coalesced float4 stores (output is never re-read).
#pragma unroll
    for (int h = 0; h < NCH; ++h) {
        f32x4 o0, o1;
#pragma unroll
        for (int j = 0; j < 4; ++j) {
            int   p  = h * 4 + j;
            int   q  = (int)((lpk[p >> 1] >> (16 * (p & 1))) & 0xffffu);  // v_bfe_u32
            float a0 = row[0][q];        // ds_read2_b32 pair
            float b0 = row[0][q + 1];
            float a1 = row[1][q];        // same vaddr, offset:16384
            float b1 = row[1][q + 1];
            o0[j] = fmaf(w1[p], b0 - a0, a0);
            o1[j] = fmaf(w1[p], b1 - a1, a1);
        }
        __builtin_nontemporal_store(o0,
            reinterpret_cast<f32x4*>(orow + h * (BLOCK * 4) + 4 * tid));
        __builtin_nontemporal_store(o1,
            reinterpret_cast<f32x4*>(orow + L_OUT + h * (BLOCK * 4) + 4 * tid));
    }
}

extern "C" void kernel_launch(void* const* d_in, const int* in_sizes, int n_in,
                              void* d_out, int out_size, void* d_ws, size_t ws_size,
                              hipStream_t stream) {
    const float* inp  = (const float*)d_in[0];
    const float* grid = (const float*)d_in[1];
    float* out = (float*)d_out;
    gs1d_kernel<<<NBLOCKS, BLOCK, 0, stream>>>(inp, grid, out);
}